// Round 16
// baseline (61.879 us; speedup 1.0000x reference)
//
#include <hip/hip_runtime.h>
#include <math.h>

// Problem constants (from reference)
#define P_TOTAL 10000
#define G_TOTAL 6400
#define C_CLS   18
#define CS_SH   3                   // cell = 8 voxels = 4 m
#define NCX     25
#define NCELL   (NCX * NCX)         // 625
#define SC_DIV  5                   // supercell = 5x5 cells (20 m)
#define NSC     25
#define SBCAP   768                 // boxes per supercell (mean ~433, +15 sd)
#define SPCAP   640                 // points per supercell (mean 400, +12 sd)
#define BCAP    256                 // boxes per cell (mean ~54)
#define PCAP    96                  // points per cell (mean 16)
#define NTHR    512
#define HB      16                  // hits per MLP batch in gather

// Workspace layout (bytes)
#define OFF_BOX  0                              // int4 boxes[6400]      102,400
#define OFF_CNT  102400                         // int cnt[64]: [0..24]=box, [32..56]=pt
#define OFF_SBL  102656                         // int sblist[25][768]    76,800 (ids)
#define OFF_SPL  179456                         // int splist[25][640]    64,000

// ---------------- K1: pack boxes + zero supercell counters ----------------
__global__ void la_pack(const float* __restrict__ means3D,
                        const float* __restrict__ scales,
                        char* __restrict__ ws) {
    int4* boxes = (int4*)(ws + OFF_BOX);
    int*  cnt   = (int*)(ws + OFF_CNT);
    int tid = blockIdx.x * 256 + threadIdx.x;
    if (tid < G_TOTAL) {
        int g = tid;
        float mx = means3D[g * 3 + 0];
        float my = means3D[g * 3 + 1];
        float mz = means3D[g * 3 + 2];
        float sx = scales[g * 3 + 0];
        float sy = scales[g * 3 + 1];
        float sz = scales[g * 3 + 2];
        // (mu - PC_MIN)/0.5 == (mu - PC_MIN)*2 exactly
        int mix = (int)((mx + 50.0f) * 2.0f);
        int miy = (int)((my + 50.0f) * 2.0f);
        int miz = (int)((mz + 5.0f) * 2.0f);
        // radii = ceil(max(s)*3.0/0.5): *3.0 rounds, *2 exact
        int r = (int)ceilf((fmaxf(fmaxf(sx, sy), sz) * 3.0f) * 2.0f);
        int w = 2 * r;
        boxes[g] = make_int4(mix - r, miy - r, miz - r, (w << 16) | g);
    } else if (tid < G_TOTAL + 64) {
        cnt[tid - G_TOTAL] = 0;
    }
}

// ---------------- K2: scatter gaussians (4 lanes each) + points into supercells ----
__global__ void la_scat(const float* __restrict__ pts,
                        char* __restrict__ ws) {
    const int4* boxes = (const int4*)(ws + OFF_BOX);
    int* cnt    = (int*)(ws + OFF_CNT);
    int* sblist = (int*)(ws + OFF_SBL);
    int* splist = (int*)(ws + OFF_SPL);
    int tid = blockIdx.x * 256 + threadIdx.x;
    if (tid < G_TOTAL * 4) {
        int g = tid >> 2, k = tid & 3;
        int4 b = boxes[g];
        int w = b.w >> 16;
        int cx0 = max(b.x, 0) >> CS_SH;
        int cx1 = min(b.x + w, 199) >> CS_SH;
        int cy0 = max(b.y, 0) >> CS_SH;
        int cy1 = min(b.y + w, 199) >> CS_SH;
        int sx0 = cx0 / SC_DIV, sx1 = cx1 / SC_DIV;   // spans <= 2 per axis
        int sy0 = cy0 / SC_DIV, sy1 = cy1 / SC_DIV;
        int dx = k & 1, dy = k >> 1;
        int sx = sx0 + dx, sy = sy0 + dy;
        if (sx <= sx1 && sy <= sy1) {
            int sc = sy * SC_DIV + sx;
            int s = atomicAdd(&cnt[sc], 1);
            if (s < SBCAP) sblist[sc * SBCAP + s] = g;
        }
    } else if (tid < G_TOTAL * 4 + P_TOTAL) {
        int p = tid - G_TOTAL * 4;
        float px = pts[p * 3 + 0];
        float py = pts[p * 3 + 1];
        int cx = ((int)((px + 50.0f) * 2.0f)) >> CS_SH;
        int cy = ((int)((py + 50.0f) * 2.0f)) >> CS_SH;
        int sc = (cy / SC_DIV) * SC_DIV + (cx / SC_DIV);
        int s = atomicAdd(&cnt[32 + sc], 1);
        if (s < SPCAP) splist[sc * SPCAP + s] = p;
    }
}

// ---------------- K3: block = cell; sweep ONLY the supercell lists, then gather ----
__global__ void __launch_bounds__(NTHR)
la_gather(const float* __restrict__ pts,
          const float* __restrict__ means3D,
          const float* __restrict__ opacities,
          const float* __restrict__ semantics,
          const float* __restrict__ cov3D,
          const char* __restrict__ ws,
          float* __restrict__ out) {
    const int4* boxes  = (const int4*)(ws + OFF_BOX);
    const int*  cnt    = (const int*)(ws + OFF_CNT);
    const int*  sblist = (const int*)(ws + OFF_SBL);
    const int*  splist = (const int*)(ws + OFF_SPL);

    __shared__ int4 sbox[BCAP];     // 4 KB
    __shared__ int  spl[PCAP];
    __shared__ int  snb, snp;

    const int t = threadIdx.x;
    const int cell = blockIdx.x;
    const int ccx = cell % NCX;
    const int ccy = cell / NCX;
    const int sc  = (ccy / SC_DIV) * SC_DIV + (ccx / SC_DIV);

    if (t == 0) { snb = 0; snp = 0; }
    __syncthreads();

    // phase 1: filter supercell's points down to this cell (~400 ids, 1 iter)
    const int npl = min(cnt[32 + sc], SPCAP);
    for (int i = t; i < npl; i += NTHR) {
        int p = splist[sc * SPCAP + i];
        float px = pts[p * 3 + 0];
        float py = pts[p * 3 + 1];
        int cx = ((int)((px + 50.0f) * 2.0f)) >> CS_SH;
        int cy = ((int)((py + 50.0f) * 2.0f)) >> CS_SH;
        if (cx == ccx && cy == ccy) {
            int s = atomicAdd(&snp, 1);
            if (s < PCAP) spl[s] = p;
        }
    }

    // phase 2: filter supercell's boxes down to this cell (~433 ids, 1 iter)
    const int nbl = min(cnt[sc], SBCAP);
    for (int i = t; i < nbl; i += NTHR) {
        int g = sblist[sc * SBCAP + i];
        int4 b = boxes[g];
        int w = b.w >> 16;
        int cx0 = max(b.x, 0) >> CS_SH;
        int cx1 = min(b.x + w, 199) >> CS_SH;
        int cy0 = max(b.y, 0) >> CS_SH;
        int cy1 = min(b.y + w, 199) >> CS_SH;
        if (ccx >= cx0 && ccx <= cx1 && ccy >= cy0 && ccy <= cy1) {
            int s = atomicAdd(&snb, 1);
            if (s < BCAP) sbox[s] = b;
        }
    }
    __syncthreads();

    const int np = min(snp, PCAP);
    const int nb = min(snb, BCAP);
    const int wv = t >> 6, lane = t & 63;      // 8 waves

    // phase 3: wave-per-point gather; lanes 0..17 accumulate classes
    for (int idx = wv; idx < np; idx += NTHR / 64) {
        int pt = spl[idx];
        float px = pts[pt * 3 + 0];
        float py = pts[pt * 3 + 1];
        float pz = pts[pt * 3 + 2];
        int pix = (int)((px + 50.0f) * 2.0f);
        int piy = (int)((py + 50.0f) * 2.0f);
        int piz = (int)((pz + 5.0f) * 2.0f);

        float acc = 0.0f;
        for (int base = 0; base < nb; base += 64) {
            int i = base + lane;
            float wgt = 0.0f;
            int gid = 0;
            if (i < nb) {
                int4 b = sbox[i];
                unsigned w  = ((unsigned)b.w) >> 16;
                unsigned ux = (unsigned)(pix - b.x);
                unsigned uy = (unsigned)(piy - b.y);
                unsigned uz = (unsigned)(piz - b.z);
                if (ux <= w && uy <= w && uz <= w) {
                    gid = b.w & 0xffff;
                    float mx = means3D[gid * 3 + 0];
                    float my = means3D[gid * 3 + 1];
                    float mz = means3D[gid * 3 + 2];
                    const float* cv = cov3D + (size_t)gid * 9;
                    float dx = px - mx, dy = py - my, dz = pz - mz;
                    float pw = -0.5f * (cv[0] * dx * dx + cv[4] * dy * dy + cv[8] * dz * dz)
                               - cv[1] * dx * dy - cv[5] * dy * dz - cv[2] * dx * dz;
                    wgt = __expf(pw) * opacities[gid];
                }
            }
            // batched hit processing: collect via shuffles, then issue all
            // semantics loads independently (breaks dependent-load chain)
            unsigned long long m = __ballot(wgt != 0.0f);
            while (m) {
                float wh[HB];
                int   gh[HB];
#pragma unroll
                for (int k = 0; k < HB; ++k) {
                    bool has = (m != 0);
                    int h = (int)__builtin_ctzll(m | 0x8000000000000000ULL);
                    float w_ = __shfl(wgt, h, 64);   // uniform index -> readlane
                    int   g_ = __shfl(gid, h, 64);
                    wh[k] = has ? w_ : 0.0f;         // wgt=0 -> fma identity
                    gh[k] = has ? g_ : 0;
                    m &= m - 1;
                }
                if (lane < C_CLS) {
#pragma unroll
                    for (int k = 0; k < HB; ++k)
                        acc = fmaf(wh[k], semantics[(size_t)gh[k] * C_CLS + lane], acc);
                }
            }
        }

        if (lane < C_CLS)
            out[(size_t)pt * C_CLS + lane] = acc;    // coalesced 72B per point
    }
}

extern "C" void kernel_launch(void* const* d_in, const int* in_sizes, int n_in,
                              void* d_out, int out_size, void* d_ws, size_t ws_size,
                              hipStream_t stream) {
    const float* pts      = (const float*)d_in[0];
    const float* means3D  = (const float*)d_in[1];
    const float* opac     = (const float*)d_in[2];
    const float* sem      = (const float*)d_in[3];
    const float* scales   = (const float*)d_in[4];
    const float* cov3D    = (const float*)d_in[5];
    float* out = (float*)d_out;
    char* ws = (char*)d_ws;

    la_pack<<<(G_TOTAL + 64 + 255) / 256, 256, 0, stream>>>(means3D, scales, ws);
    la_scat<<<(G_TOTAL * 4 + P_TOTAL + 255) / 256, 256, 0, stream>>>(pts, ws);
    la_gather<<<NCELL, NTHR, 0, stream>>>(pts, means3D, opac, sem, cov3D, ws, out);
}

// Round 17
// 28.234 us; speedup vs baseline: 2.1917x; 2.1917x over previous
//
#include <hip/hip_runtime.h>
#include <math.h>

// Problem constants (from reference)
#define P_TOTAL 10000
#define G_TOTAL 6400
#define C_CLS   18
#define CS_SH   3                   // cell = 8 voxels = 4 m
#define NCX     25
#define NCELL   (NCX * NCX)         // 625
#define BCAP    256                 // boxes per cell (mean ~54, max ~150)
#define PCAP    96                  // points per cell (mean 16, max ~40)
#define NTHR    512                 // 8 waves per block
#define HB      16                  // hits processed per batch (MLP width)

// Single fused kernel: block = cell. Vectorized sweeps, then wave-per-point
// gather with BATCHED hit processing (collect via shuffles, then issue all
// semantics loads independently -> breaks the serial dependent-load chain).
// Session optimum (R13 = 28.2 us): 1 graph node (~7-9 us/node overhead measured),
// full-input sweep per block is the 1-node-structural cost (cross-block
// alternatives all slower: grid.sync ~120us, spin barrier ~75us, 3-node
// binning ~33-35us, supercell atomics 62us, block-local pruning 45-52us).
__global__ void __launch_bounds__(NTHR)
la_cell3(const float* __restrict__ pts,
         const float* __restrict__ means3D,
         const float* __restrict__ opacities,
         const float* __restrict__ semantics,
         const float* __restrict__ scales,
         const float* __restrict__ cov3D,
         float* __restrict__ out) {
    __shared__ int4 sbox[BCAP];     // 4 KB
    __shared__ int  splist[PCAP];
    __shared__ int  snb, snp;

    const int t = threadIdx.x;
    const int cell = blockIdx.x;
    const int ccx = cell % NCX;
    const int ccy = cell / NCX;

    if (t == 0) { snb = 0; snp = 0; }
    __syncthreads();

    // phase 1: collect this cell's points — 4 points per iteration
    const float4* p4 = (const float4*)pts;
    for (int j = t; j < P_TOTAL / 4; j += NTHR) {
        float4 a = p4[j * 3 + 0];
        float4 b = p4[j * 3 + 1];
        float4 c = p4[j * 3 + 2];
        float pxs[4] = {a.x, a.w, b.z, c.y};
        float pys[4] = {a.y, b.x, b.w, c.z};
#pragma unroll
        for (int q = 0; q < 4; ++q) {
            int cx = ((int)((pxs[q] + 50.0f) * 2.0f)) >> CS_SH;
            int cy = ((int)((pys[q] + 50.0f) * 2.0f)) >> CS_SH;
            if (cx == ccx && cy == ccy) {
                int s = atomicAdd(&snp, 1);
                if (s < PCAP) splist[s] = j * 4 + q;
            }
        }
    }

    // phase 2: collect boxes overlapping this cell — 4 gaussians per iteration
    const float4* m4 = (const float4*)means3D;
    const float4* s4 = (const float4*)scales;
    for (int j = t; j < G_TOTAL / 4; j += NTHR) {
        float4 ma = m4[j * 3 + 0], mb = m4[j * 3 + 1], mc = m4[j * 3 + 2];
        float4 sa = s4[j * 3 + 0], sb = s4[j * 3 + 1], sc = s4[j * 3 + 2];
        float mxs[4] = {ma.x, ma.w, mb.z, mc.y};
        float mys[4] = {ma.y, mb.x, mb.w, mc.z};
        float mzs[4] = {ma.z, mb.y, mc.x, mc.w};
        float sxs[4] = {sa.x, sa.w, sb.z, sc.y};
        float sys[4] = {sa.y, sb.x, sb.w, sc.z};
        float szs[4] = {sa.z, sb.y, sc.x, sc.w};
#pragma unroll
        for (int q = 0; q < 4; ++q) {
            // (mu - PC_MIN)/0.5 == (mu - PC_MIN)*2 exactly
            int mix = (int)((mxs[q] + 50.0f) * 2.0f);
            int miy = (int)((mys[q] + 50.0f) * 2.0f);
            int miz = (int)((mzs[q] + 5.0f) * 2.0f);
            // radii = ceil(max(s)*3.0/0.5): *3.0 rounds, *2 exact
            int r = (int)ceilf((fmaxf(fmaxf(sxs[q], sys[q]), szs[q]) * 3.0f) * 2.0f);
            int w = 2 * r;
            int minx = mix - r, miny = miy - r, minz = miz - r;
            int cx0 = max(minx, 0) >> CS_SH;
            int cx1 = min(minx + w, 199) >> CS_SH;
            int cy0 = max(miny, 0) >> CS_SH;
            int cy1 = min(miny + w, 199) >> CS_SH;
            if (ccx >= cx0 && ccx <= cx1 && ccy >= cy0 && ccy <= cy1) {
                int s = atomicAdd(&snb, 1);
                if (s < BCAP)
                    sbox[s] = make_int4(minx, miny, minz, (w << 16) | (j * 4 + q));
            }
        }
    }
    __syncthreads();

    const int np = min(snp, PCAP);
    const int nb = min(snb, BCAP);
    const int wv = t >> 6, lane = t & 63;      // 8 waves per block

    // phase 3: wave-per-point gather; lanes 0..17 accumulate classes.
    for (int idx = wv; idx < np; idx += NTHR / 64) {
        int pt = splist[idx];
        float px = pts[pt * 3 + 0];
        float py = pts[pt * 3 + 1];
        float pz = pts[pt * 3 + 2];
        int pix = (int)((px + 50.0f) * 2.0f);
        int piy = (int)((py + 50.0f) * 2.0f);
        int piz = (int)((pz + 5.0f) * 2.0f);

        float acc = 0.0f;
        for (int base = 0; base < nb; base += 64) {
            int i = base + lane;
            float wgt = 0.0f;
            int gid = 0;
            if (i < nb) {
                int4 b = sbox[i];
                unsigned w  = ((unsigned)b.w) >> 16;
                unsigned ux = (unsigned)(pix - b.x);
                unsigned uy = (unsigned)(piy - b.y);
                unsigned uz = (unsigned)(piz - b.z);
                if (ux <= w && uy <= w && uz <= w) {
                    gid = b.w & 0xffff;
                    float mx = means3D[gid * 3 + 0];
                    float my = means3D[gid * 3 + 1];
                    float mz = means3D[gid * 3 + 2];
                    const float* cv = cov3D + (size_t)gid * 9;
                    float dx = px - mx, dy = py - my, dz = pz - mz;
                    float pw = -0.5f * (cv[0] * dx * dx + cv[4] * dy * dy + cv[8] * dz * dz)
                               - cv[1] * dx * dy - cv[5] * dy * dz - cv[2] * dx * dz;
                    wgt = __expf(pw) * opacities[gid];
                }
            }

            // batched hit processing: collect up to HB hits with shuffles only,
            // then issue all HB semantics loads independently (MLP ~13).
            unsigned long long m = __ballot(wgt != 0.0f);
            while (m) {
                float wh[HB];
                int   gh[HB];
#pragma unroll
                for (int k = 0; k < HB; ++k) {
                    bool has = (m != 0);
                    int h = (int)__builtin_ctzll(m | 0x8000000000000000ULL);
                    float w_ = __shfl(wgt, h, 64);   // uniform index -> readlane
                    int   g_ = __shfl(gid, h, 64);
                    wh[k] = has ? w_ : 0.0f;         // wgt=0 -> fma is identity
                    gh[k] = has ? g_ : 0;            // dummy load hits sem[0..17]
                    m &= m - 1;
                }
                if (lane < C_CLS) {
#pragma unroll
                    for (int k = 0; k < HB; ++k)
                        acc = fmaf(wh[k], semantics[(size_t)gh[k] * C_CLS + lane], acc);
                }
            }
        }

        if (lane < C_CLS)
            out[(size_t)pt * C_CLS + lane] = acc;   // coalesced 72B per point
    }
}

extern "C" void kernel_launch(void* const* d_in, const int* in_sizes, int n_in,
                              void* d_out, int out_size, void* d_ws, size_t ws_size,
                              hipStream_t stream) {
    const float* pts      = (const float*)d_in[0];
    const float* means3D  = (const float*)d_in[1];
    const float* opac     = (const float*)d_in[2];
    const float* sem      = (const float*)d_in[3];
    const float* scales   = (const float*)d_in[4];
    const float* cov3D    = (const float*)d_in[5];
    float* out = (float*)d_out;

    la_cell3<<<NCELL, NTHR, 0, stream>>>(pts, means3D, opac, sem, scales, cov3D, out);
}